// Round 5
// baseline (127.739 us; speedup 1.0000x reference)
//
#include <hip/hip_runtime.h>
#include <math.h>

// CIRNet, barrier-free 2-kernel split, single-wave prep blocks:
// T=1048576 rows x 18 feats -> r_predicts/regs/dts.
// prep: 4096 blocks x 64 threads (1 wave). Per block: two 32-quad stage passes issued
//   back-to-back into separate LDS buffers (40 global_load_lds dwordx4 in flight),
//   ONE wave-local s_waitcnt vmcnt(0), then full-wave extraction (lanes 0-31 buf0,
//   32-63 buf1; buffer bases bank-congruent -> 2-way = free). No __syncthreads at all.
//   Writes regs/dts, per-step (d,c), wave-exclusive prefix, per-block (=wave) aggregate.
// final: 1024 blocks x 256 threads, barrier-free: every block redundantly scans the
//   4096 aggregates (32 KB, L2-hot; 16 register-held sequential composes per thread),
//   picks its waves' prep-block prefixes, replays 4 FSTEPs, stores r_predicts.
// All FP dot/step math identical to the validated kernels; scan granularity 64 quads.
#define NSTEPS   1048575
#define FEAT     18
#define NB1      4096                // prep blocks (1 wave each)
#define NT1      64
#define NQ       (NB1 * NT1)         // 262144 quads x 4 rows = 1048576 rows
#define NB2      1024                // final blocks
#define NT2      256
#define SLOTS    608                 // 19 * 32 float4 slots per stage pass
#define WBYTES   (SLOTS * 16)        // 9728 B per pass buffer

#define GLDS16(g, l) \
    __builtin_amdgcn_global_load_lds((const __attribute__((address_space(1))) void*)(g), \
                                     (__attribute__((address_space(3))) void*)(l), 16, 0, 0)

#define WAIT_VM0()   asm volatile("s_waitcnt vmcnt(0)" ::: "memory")

// one step + derivative-product update (identical math to validated kernel)
#define GSTEP(dd, cc) { \
    float a   = fmaf(-k, (dd), 1.f); \
    float b   = kth * (dd); \
    float ar  = fabsf(r); \
    float sq  = sqrtf(ar); \
    float inv = (ar > 1e-30f) ? rsqrtf(ar) : 0.f; \
    float g   = fmaf(0.5f * (cc), copysignf(inv, r), a); \
    r = fmaf((cc), sq, fmaf(a, r, b)); \
    P *= g; }

#define FSTEP(dd, cc) { \
    float a = fmaf(-k, (dd), 1.f); \
    float b = kth * (dd); \
    rr = fmaf((cc), sqrtf(fabsf(rr)), fmaf(a, rr, b)); }

// sig & eps dot-products, same fma order as validated kernel
#define DOTSE(S0,S1,S2,S3,S4,S5,S6,S7, E0,E1,E2,E3,E4,E5,E6,E7, sigv, epv) { \
    float sig_ = sb0; \
    sig_ = fmaf((S0), sw0, sig_); sig_ = fmaf((S1), sw1, sig_); \
    sig_ = fmaf((S2), sw2, sig_); sig_ = fmaf((S3), sw3, sig_); \
    sig_ = fmaf((S4), sw4, sig_); sig_ = fmaf((S5), sw5, sig_); \
    sig_ = fmaf((S6), sw6, sig_); sig_ = fmaf((S7), sw7, sig_); \
    float ep_ = 0.f; \
    ep_ = fmaf((E0), ew0, ep_); ep_ = fmaf((E1), ew1, ep_); \
    ep_ = fmaf((E2), ew2, ep_); ep_ = fmaf((E3), ew3, ep_); \
    ep_ = fmaf((E4), ew4, ep_); ep_ = fmaf((E5), ew5, ep_); \
    ep_ = fmaf((E6), ew6, ep_); ep_ = fmaf((E7), ew7, ep_); \
    (sigv) = sig_; (epv) = ep_; }

// read one padded quad (18 float4 at stride-19 slots) from lw and compute coefficients
#define EXTRACT_COMPUTE(JROW) { \
    const float4* sr = (const float4*)lw + 19 * (JROW); \
    float4 u0 = sr[0],  u1  = sr[1],  u2  = sr[2],  u3  = sr[3],  u4  = sr[4]; \
    float4 u5 = sr[5],  u6  = sr[6],  u7  = sr[7],  u8  = sr[8]; \
    float4 u9 = sr[9],  u10 = sr[10], u11 = sr[11], u12 = sr[12], u13 = sr[13]; \
    float4 u14 = sr[14], u15 = sr[15], u16 = sr[16], u17 = sr[17]; \
    tfirst = u0.x; t3 = u13.z; \
    d0 = u4.z  - u0.x;  d1 = u9.x - u4.z;  d2 = u13.z - u9.x; \
    float ep0, ep1, ep2; \
    DOTSE(u0.z,u0.w,u1.x,u1.y,u1.z,u1.w,u2.x,u2.y, \
          u2.z,u2.w,u3.x,u3.y,u3.z,u3.w,u4.x,u4.y, sig0, ep0) \
    DOTSE(u5.x,u5.y,u5.z,u5.w,u6.x,u6.y,u6.z,u6.w, \
          u7.x,u7.y,u7.z,u7.w,u8.x,u8.y,u8.z,u8.w, sig1, ep1) \
    DOTSE(u9.z,u9.w,u10.x,u10.y,u10.z,u10.w,u11.x,u11.y, \
          u11.z,u11.w,u12.x,u12.y,u12.z,u12.w,u13.x,u13.y, sig2, ep2) \
    DOTSE(u14.x,u14.y,u14.z,u14.w,u15.x,u15.y,u15.z,u15.w, \
          u16.x,u16.y,u16.z,u16.w,u17.x,u17.y,u17.z,u17.w, sig3, ep3) \
    c0v = sig0 * ep0 * sqrtf(fabsf(d0)); \
    c1v = sig1 * ep1 * sqrtf(fabsf(d1)); \
    c2v = sig2 * ep2 * sqrtf(fabsf(d2)); }

__device__ __forceinline__ void stage_pass(const float4* __restrict__ base4,
                                           char* lds_buf, int lane)
{
    int jr = lane / 19;                 // quad within pass
    int ic = lane - 19 * jr;            // padded col
#pragma unroll
    for (int i = 0; i < 10; ++i) {
        int col = (ic == 18) ? 17 : ic; // pad slot -> duplicate col 17 (in-bounds)
        const float4* src = base4 + (18 * jr + col);
        if (i < 9) {
            GLDS16(src, lds_buf + i * 1024);
        } else if (lane < 32) {         // partial tail: slots 576..607 (exec-masked)
            GLDS16(src, lds_buf + 9 * 1024);
        }
        jr += 3; ic += 7;               // advance slot by 64 = 3*19 + 7
        if (ic >= 19) { ic -= 19; ++jr; }
    }
}

__device__ __forceinline__ void wave_scan_affine(float& A, float& B, int lane) {
#pragma unroll
    for (int d = 1; d < 64; d <<= 1) {
        float pA = __shfl_up(A, d, 64);
        float pB = __shfl_up(B, d, 64);
        if (lane >= d) { B = fmaf(A, pB, B); A *= pA; }
    }
}

// ---------------- K1: stage (dbuf) + coeffs + regs/dts + dc + wave scan ----------------
__global__ void __launch_bounds__(NT1) cir_prep(
    const float* __restrict__ trace,
    const float* __restrict__ sW, const float* __restrict__ sb,
    const float* __restrict__ eW, const float* __restrict__ kp,
    const float* __restrict__ thp,
    float* __restrict__ out,
    float2* __restrict__ dc, float2* __restrict__ pref, float2* __restrict__ agg)
{
    __shared__ __align__(16) char stage[2 * WBYTES];        // 19456 B -> 8 blocks/CU

    const int lane = threadIdx.x;                           // 1 wave per block
    const int bid = blockIdx.x;
    const long c = (long)bid * NT1 + lane;                  // thread's quad index
    const float4* t4 = (const float4*)trace;
    const long blockQuad = (long)bid * NT1;

    // both passes issued back-to-back: 40 DMA loads in flight, ONE wait below
    stage_pass(t4 + blockQuad * 18,        stage,          lane);
    stage_pass(t4 + (blockQuad + 32) * 18, stage + WBYTES, lane);

    // scalar params load under the DMA latency
    const float k = kp[0], th = thp[0], kth = k * th, tkth2 = 2.f * kth;
    const float sb0 = sb[0];
    const float sw0 = sW[0], sw1 = sW[1], sw2 = sW[2], sw3 = sW[3];
    const float sw4 = sW[4], sw5 = sW[5], sw6 = sW[6], sw7 = sW[7];
    const float ew0 = eW[0], ew1 = eW[1], ew2 = eW[2], ew3 = eW[3];
    const float ew4 = eW[4], ew5 = eW[5], ew6 = eW[6], ew7 = eW[7];
    const float t0g = trace[0], r0v = trace[1];

    float tfirst, t3, d0, d1, d2, c0v, c1v, c2v, sig0, sig1, sig2, sig3, ep3;

    WAIT_VM0();                                 // single drain: both buffers resident
    {
        char* lw = stage + ((lane < 32) ? 0 : WBYTES);   // bank-congruent bases (2-way)
        const int jrow = lane & 31;
        EXTRACT_COMPUTE(jrow)                   // all 64 lanes active
    }

    // t of next quad's first row: shuffle; lane 63 loads (1 txn/wave)
    float tnext = __shfl_down(tfirst, 1, 64);
    if (lane == 63)
        tnext = (c + 1 < (long)NQ) ? trace[(c * 4 + 4) * FEAT] : 0.f;
    float d3 = tnext - t3;
    const long n0 = c * 4;
    float c3v = sig3 * ep3 * sqrtf(fabsf(d3));
    if (n0 + 4 > NSTEPS) { d3 = 0.f; c3v = 0.f; }           // step NSTEPS is pad

    // regs/dts stores
    out[NSTEPS + n0 + 0] = fmaf(-sig0, sig0, tkth2);
    out[NSTEPS + n0 + 1] = fmaf(-sig1, sig1, tkth2);
    out[NSTEPS + n0 + 2] = fmaf(-sig2, sig2, tkth2);
    out[2L * NSTEPS + n0 + 0] = d0;
    out[2L * NSTEPS + n0 + 1] = d1;
    out[2L * NSTEPS + n0 + 2] = d2;
    if (n0 + 4 <= NSTEPS) {
        out[NSTEPS + n0 + 3] = fmaf(-sig3, sig3, tkth2);
        out[2L * NSTEPS + n0 + 3] = d3;
    }

    // per-step coefficients for K2's replay
    float4* dc4 = (float4*)dc;
    dc4[2 * c]     = make_float4(d0, c0v, d1, c1v);
    dc4[2 * c + 1] = make_float4(d2, c2v, d3, c3v);

    // affine map for this quad: r -> A*r + B (seed + 4 Newton-linearized steps)
    float s = th + (r0v - th) * __expf(-k * (tfirst - t0g));
    float r = s, P = 1.f;
    GSTEP(d0, c0v)
    GSTEP(d1, c1v)
    GSTEP(d2, c2v)
    GSTEP(d3, c3v)
    float A = P, Bv = fmaf(-P, s, r);

    // wave scan == block scan (single wave); no __syncthreads anywhere
    float iA = A, iB = Bv;
    wave_scan_affine(iA, iB, lane);
    float eA = __shfl_up(iA, 1, 64), eB = __shfl_up(iB, 1, 64);
    if (lane == 0) { eA = 1.f; eB = 0.f; }
    pref[c] = make_float2(eA, eB);              // wave-exclusive prefix
    if (lane == 63) agg[bid] = make_float2(iA, iB);   // block (=wave) aggregate
}

// ---------------- K2: barrier-free global scan + replay ----------------
__global__ void __launch_bounds__(NT2) cir_final(
    const float* __restrict__ trace,
    const float* __restrict__ kp, const float* __restrict__ thp,
    const float2* __restrict__ dc, const float2* __restrict__ pref,
    const float2* __restrict__ agg,
    float* __restrict__ out)
{
    __shared__ float2 incs[NB1];        // 32 KB inclusive scan of 4096 wave aggregates
    __shared__ float wA2[4], wB2[4];

    const int tid = threadIdx.x, lane = tid & 63, wid = tid >> 6, bid = blockIdx.x;
    const long c = (long)bid * NT2 + tid;
    const float k = kp[0], th = thp[0], kth = k * th;
    const float r0v = trace[1];

    // every block scans all 4096 aggregates: 16 register-held sequential per thread
    float2 av[16];
#pragma unroll
    for (int i = 0; i < 16; ++i) av[i] = agg[16 * tid + i];
    float cA = av[0].x, cB = av[0].y;
#pragma unroll
    for (int i = 1; i < 16; ++i) { cB = fmaf(av[i].x, cB, av[i].y); cA *= av[i].x; }

    float iA = cA, iB = cB;                           // inclusive over 16-agg chunks
    wave_scan_affine(iA, iB, lane);
    if (lane == 63) { wA2[wid] = iA; wB2[wid] = iB; }
    __syncthreads();
    if (wid == 0) {
        float aA = (lane < 4) ? wA2[lane] : 1.f;
        float aB = (lane < 4) ? wB2[lane] : 0.f;
        wave_scan_affine(aA, aB, lane);
        if (lane < 4) { wA2[lane] = aA; wB2[lane] = aB; }
    }
    __syncthreads();
    float weA = 1.f, weB = 0.f;
    if (wid > 0) { weA = wA2[wid - 1]; weB = wB2[wid - 1]; }
    float eA = __shfl_up(iA, 1, 64), eB = __shfl_up(iB, 1, 64);
    if (lane == 0) { eA = 1.f; eB = 0.f; }
    float EA = eA * weA, EB = fmaf(eA, weB, eB);      // exclusive prefix of chunk 16*tid

    // inclusive values for this thread's 16 aggregates -> LDS
    float xA = EA, xB = EB;
#pragma unroll
    for (int i = 0; i < 16; ++i) {
        xB = fmaf(av[i].x, xB, av[i].y); xA *= av[i].x;
        incs[16 * tid + i] = make_float2(xA, xB);
    }
    __syncthreads();

    // this thread's prep-block (= wave of 64 quads) is bid*4 + wid
    const int pblk = 4 * bid + wid;
    float beA = 1.f, beB = 0.f;
    if (pblk > 0) { float2 p = incs[pblk - 1]; beA = p.x; beB = p.y; }

    // replay this thread's 4 steps from the corrected start
    const float4* dc4 = (const float4*)dc;
    float4 q0 = dc4[2 * c], q1 = dc4[2 * c + 1];
    float2 pr = pref[c];
    float FA = pr.x * beA;
    float FB = fmaf(pr.x, beB, pr.y);
    float rr = fmaf(FA, r0v, FB);
    float4 ov;
    FSTEP(q0.x, q0.y) ov.x = rr;
    FSTEP(q0.z, q0.w) ov.y = rr;
    FSTEP(q1.x, q1.y) ov.z = rr;
    FSTEP(q1.z, q1.w) ov.w = rr;
    long nb = 4 * c;
    if (nb + 4 <= NSTEPS) {
        *(float4*)(out + nb) = ov;
    } else {                        // last thread only (step NSTEPS is pad)
        out[nb + 0] = ov.x;
        out[nb + 1] = ov.y;
        out[nb + 2] = ov.z;
    }
}

extern "C" void kernel_launch(void* const* d_in, const int* in_sizes, int n_in,
                              void* d_out, int out_size, void* d_ws, size_t ws_size,
                              hipStream_t stream)
{
    const float* trace = (const float*)d_in[0];
    const float* sW    = (const float*)d_in[1];
    const float* sb    = (const float*)d_in[2];
    const float* eW    = (const float*)d_in[3];
    const float* kp    = (const float*)d_in[4];
    const float* thp   = (const float*)d_in[5];
    float* out = (float*)d_out;

    float2* dc   = (float2*)d_ws;           // 4*NQ float2 = 8 MB
    float2* pref = dc + 4L * NQ;            // NQ float2 = 2 MB
    float2* agg  = pref + NQ;               // NB1 float2 = 32 KB

    cir_prep<<<NB1, NT1, 0, stream>>>(trace, sW, sb, eW, kp, thp, out, dc, pref, agg);
    cir_final<<<NB2, NT2, 0, stream>>>(trace, kp, thp, dc, pref, agg, out);
}